// Round 4
// baseline (692.429 us; speedup 1.0000x reference)
//
#include <hip/hip_runtime.h>

#define CAP 32
#define K 16          // steps per batch
#define R 2           // batches per group (barrier period = R*K steps)
#define RING 4        // obuf ring slots (>= 2R)

// ---------------------------------------------------------------------------
// Kernel 1: runtime sparsification of W1 (general; for this input nnz=1/row).
// ---------------------------------------------------------------------------
__global__ void sparsify_kernel(const float* __restrict__ W1, int N,
                                int* __restrict__ cnts, int* __restrict__ cols,
                                float* __restrict__ wts) {
  __shared__ int scnt;
  const int row = blockIdx.x;
  if (threadIdx.x == 0) scnt = 0;
  __syncthreads();
  const float* wr = W1 + (long)row * N;
  for (int k = threadIdx.x; k < N; k += blockDim.x) {
    float w = wr[k];
    if (w != 0.0f) {
      int slot = atomicAdd(&scnt, 1);
      if (slot < CAP) {
        cols[row * CAP + slot] = k;
        wts[row * CAP + slot] = w;
      }
    }
  }
  __syncthreads();
  if (threadIdx.x == 0) {
    cnts[row] = scnt;
    if (scnt == 0) { cols[row * CAP] = 0; wts[row * CAP] = 0.0f; }
  }
}

// ---------------------------------------------------------------------------
// One Izhikevich step, bitwise numpy op order (contract off at kernel scope).
// ---------------------------------------------------------------------------
#define IZH_STEP(xv, sout)                        \
  {                                               \
    const float I = w0 * (xv);                    \
    float t1 = 0.04f * v;                         \
    float t2 = t1 * v;                            \
    float t3 = 5.0f * v;                          \
    float t4 = t2 + t3;                           \
    float t5 = t4 + 140.0f;                       \
    float t6 = t5 - u;                            \
    float t7 = t6 + I;                            \
    float vn = v + t7;      /* dt==1: exact */    \
    float q1 = bn * v;                            \
    float q2 = q1 - u;                            \
    float q3 = Pn * q2;                           \
    float un = u + q3;                            \
    float df = vn - thn;                          \
    bool sp = df > 0.0f;                          \
    v = sp ? cn : vn;       /* == vn*(1-s)+c*s */ \
    u = un + (sp ? dn : 0.0f); /* == un + d*s */  \
    sout = sp ? 1.0f : 0.0f;                      \
  }

// ---------------------------------------------------------------------------
// Kernel 2: producer/consumer pipelined recurrence.
// Block = 256 thr (4 waves, 1 per SIMD) per 64 neurons; grid = N/64 blocks.
//   wave0: compute. Loads its own x from global into 2 register banks with a
//          full-group (~2000 cyc) prefetch distance (HBM latency hidden, no
//          LDS round-trip, no touch kernel needed). 3 ds_write_b32 per step.
//   wave1/2/3: s/v/u writers — drain group g-1's obuf slots as b128 reads +
//          dwordx4 stores while compute runs group g. Register reuse distance
//          = 1 group, so store WAR waits hit retired ops.
// One barrier per R*K=32 steps.
// ---------------------------------------------------------------------------
__global__ void __launch_bounds__(256) izh_pipe_kernel(
    const float* __restrict__ X, const float* __restrict__ state,
    const float* __restrict__ a, const float* __restrict__ b,
    const float* __restrict__ c, const float* __restrict__ d,
    const float* __restrict__ th, const float* __restrict__ dtv,
    const float* __restrict__ W1,
    const int* __restrict__ cnts, const int* __restrict__ cols,
    const float* __restrict__ wts,
    float* __restrict__ o_s, float* __restrict__ o_st,
    int T, int N)
{
#pragma clang fp contract(off)
  __shared__ float obuf[RING][K][3][64];   // 48 KB: [slot][step][s,v,u][lane]

  const int wid  = threadIdx.x >> 6;
  const int lane = threadIdx.x & 63;
  const int base = blockIdx.x * 64;
  const int gn   = base + lane;            // this lane's neuron (all waves)
  const int B    = T / K;                  // full batches
  const int G    = B / R;                  // full groups
  const long N2  = 2L * N;

  // ---- block-uniform path decision: every wave ballots the SAME neuron set
  bool elig = (base + 64 <= N) && ((N & 3) == 0);
  if (elig) elig = (cnts[gn] == 1) && (dtv[gn] == 1.0f);
  const bool fast = (__ballot(elig) == ~0ULL);

  if (fast) {
    // ---- compute-wave persistent state ----
    float v = 0.f, u = 0.f, bn = 0.f, cn = 0.f, dn = 0.f;
    float thn = 0.f, Pn = 0.f, w0 = 0.f;
    int c0l = 0;
    float xA[R][K], xB[R][K];              // two group-sized x register banks

    if (wid == 0) {
      v = state[gn]; u = state[N + gn];
      bn = b[gn]; cn = c[gn]; dn = d[gn]; thn = th[gn];
      Pn = dtv[gn] * a[gn];                // same operands/order as ref's dt*a
      w0 = wts[gn * CAP];
      c0l = cols[gn * CAP];
      // preload group 0 -> xA, group 1 -> xB (coalesced: c0l == gn here)
      if (G > 0) {
#pragma unroll
        for (int j = 0; j < R; ++j)
#pragma unroll
          for (int i = 0; i < K; ++i)
            xA[j][i] = X[(size_t)((0 * R + j) * K + i) * N + c0l];
      }
      if (G > 1) {
#pragma unroll
        for (int j = 0; j < R; ++j)
#pragma unroll
          for (int i = 0; i < K; ++i)
            xB[j][i] = X[(size_t)((1 * R + j) * K + i) * N + c0l];
      }
    }

    // compute one group from bank xc, then refill xc for group g+2
    auto comp_group = [&](int g, float (&xc)[R][K]) {
#pragma unroll
      for (int j = 0; j < R; ++j) {
        const int bb = g * R + j;
        float* ob = &obuf[bb & (RING - 1)][0][0][lane];
#pragma unroll
        for (int i = 0; i < K; ++i) {
          float s_;
          IZH_STEP(xc[j][i], s_);
          ob[i * 192]       = s_;
          ob[i * 192 + 64]  = v;
          ob[i * 192 + 128] = u;
        }
      }
      if (g + 2 < G) {                     // refill this bank, 2-group distance
#pragma unroll
        for (int j = 0; j < R; ++j)
#pragma unroll
          for (int i = 0; i < K; ++i)
            xc[j][i] = X[(size_t)(((g + 2) * R + j) * K + i) * N + c0l];
      }
    };

    // writer: 16 rows of batch bb, plane cidx, dest P (row stride RS)
    auto store4 = [&](float* P, long RS, int bb, int cidx) {
      const int r = lane >> 4, j4 = lane & 15;
      const int t0 = bb * K, slot = bb & (RING - 1);
#pragma unroll
      for (int i = 0; i < K; i += 4) {
        const int t = t0 + i + r;
        float4 val = *(const float4*)&obuf[slot][i + r][cidx][4 * j4];
        *(float4*)(P + (size_t)t * RS + base + 4 * j4) = val;
      }
    };

    for (int g = 0; g < G; ++g) {
      if (wid == 0) {
        if ((g & 1) == 0) comp_group(g, xA);
        else              comp_group(g, xB);
      } else if (g > 0) {
        const int b0 = (g - 1) * R;
        if (wid == 1)      { for (int j = 0; j < R; ++j) store4(o_s, N, b0 + j, 0); }
        else if (wid == 2) { for (int j = 0; j < R; ++j) store4(o_st, N2, b0 + j, 1); }
        else               { for (int j = 0; j < R; ++j) store4(o_st + N, N2, b0 + j, 2); }
      }
      __syncthreads();
    }

    // -------- epilogue: drain last group --------
    if (G > 0) {
      const int b0 = (G - 1) * R;
      if (wid == 1)      { for (int j = 0; j < R; ++j) store4(o_s, N, b0 + j, 0); }
      else if (wid == 2) { for (int j = 0; j < R; ++j) store4(o_st, N2, b0 + j, 1); }
      else if (wid == 3) { for (int j = 0; j < R; ++j) store4(o_st + N, N2, b0 + j, 2); }
    }

    // -------- leftover steps (T % (R*K) != 0): wave0, direct global --------
    if (wid == 0) {
      const float* xp = X + c0l;
      for (int t = G * R * K; t < T; ++t) {
        const float xv = xp[(size_t)t * N];
        float s_;
        IZH_STEP(xv, s_);
        o_s[(size_t)t * N + gn] = s_;
        o_st[(size_t)t * N2 + gn] = v;
        o_st[(size_t)t * N2 + N + gn] = u;
      }
    }
  } else {
    // ---- general fallback: wave0 threads only, any cnt / dt (no barriers) --
    if (wid != 0 || gn >= N) return;
    float v = state[gn], u = state[N + gn];
    const float bn = b[gn], cn = c[gn], dn = d[gn];
    const float thn = th[gn], dtn = dtv[gn];
    const float Pn = dtn * a[gn];
    const int cnt = cnts[gn];
    for (int t = 0; t < T; ++t) {
      float I = 0.0f;
      if (cnt <= CAP) {
        for (int j = 0; j < cnt; ++j)
          I = I + wts[gn * CAP + j] * X[(size_t)t * N + cols[gn * CAP + j]];
      } else {
        const float* wr = W1 + (size_t)gn * N;
        const float* xr = X + (size_t)t * N;
        for (int kk = 0; kk < N; ++kk) I = I + wr[kk] * xr[kk];
      }
      float t1 = 0.04f * v; float t2 = t1 * v; float t3 = 5.0f * v;
      float t4 = t2 + t3; float t5 = t4 + 140.0f; float t6 = t5 - u;
      float t7 = t6 + I; float t8 = dtn * t7; float vn = v + t8;
      float q1 = bn * v; float q2 = q1 - u; float q3 = Pn * q2; float un = u + q3;
      float df = vn - thn; bool sp = df > 0.0f;
      v = sp ? cn : vn; u = un + (sp ? dn : 0.0f);
      o_s[(size_t)t * N + gn] = sp ? 1.0f : 0.0f;
      o_st[(size_t)t * N2 + gn] = v;
      o_st[(size_t)t * N2 + N + gn] = u;
    }
  }
}

// ---------------------------------------------------------------------------
// Kernel 3: r[t] = W2 @ s[t], 16 rows per block, float4 reads.
// Exact: terms are 20*{0,1}, all partial sums < 2^24.
// ---------------------------------------------------------------------------
__global__ void __launch_bounds__(256) decode_dot_kernel(
    const float* __restrict__ o_s, const float* __restrict__ W2,
    float* __restrict__ r, int T, int N) {
  __shared__ float red[4];
  const int tid = threadIdx.x;
  const int t0 = blockIdx.x * 16;
  for (int tt = 0; tt < 16; ++tt) {
    const int t = t0 + tt;
    if (t >= T) break;                      // block-uniform
    const float* srow = o_s + (size_t)t * N;
    float p = 0.0f;
    for (int n = 4 * tid; n + 3 < N; n += 4 * 256) {
      float4 s4 = *(const float4*)(srow + n);
      float4 w4 = *(const float4*)(W2 + n);
      p += w4.x * s4.x; p += w4.y * s4.y; p += w4.z * s4.z; p += w4.w * s4.w;
    }
    if (tid < (N & 3)) { int n = (N & ~3) + tid; p += W2[n] * srow[n]; }
    for (int off = 32; off > 0; off >>= 1) p += __shfl_down(p, off);
    if ((tid & 63) == 0) red[tid >> 6] = p;
    __syncthreads();
    if (tid == 0) r[t] = red[0] + red[1] + red[2] + red[3];
    __syncthreads();
  }
}

// ---------------------------------------------------------------------------
// Kernel 4: dm[t] = leak*dm[t-1] + r[t], chunked affine scan (1 block, 64 thr)
// Tolerance on decoded output is large; reassociation across chunks is fine.
// ---------------------------------------------------------------------------
__global__ void decode_scan_kernel(const float* __restrict__ r,
                                   const float* __restrict__ leakp,
                                   float* __restrict__ out, int T) {
  __shared__ float Bsh[64], Ssh[64];
  const float leakv = leakp[0];
  const int i = threadIdx.x;                 // 0..63
  const int chunk = (T + 63) / 64;
  const int t0 = i * chunk;
  float B = 0.0f;
  for (int j = 0; j < chunk; ++j) {
    int t = t0 + j;
    if (t < T) B = leakv * B + r[t];
  }
  Bsh[i] = B;
  float A = 1.0f, p = leakv; int e = chunk;
  while (e) { if (e & 1) A *= p; p *= p; e >>= 1; }
  __syncthreads();
  if (i == 0) {
    float dm = 0.0f;
    for (int k = 0; k < 64; ++k) { Ssh[k] = dm; dm = A * dm + Bsh[k]; }
  }
  __syncthreads();
  float dm = Ssh[i];
  for (int j = 0; j < chunk; ++j) {
    int t = t0 + j;
    if (t < T) { dm = leakv * dm + r[t]; out[t] = dm; }
  }
}

// ---------------------------------------------------------------------------
extern "C" void kernel_launch(void* const* d_in, const int* in_sizes, int n_in,
                              void* d_out, int out_size, void* d_ws, size_t ws_size,
                              hipStream_t stream) {
  const float* X  = (const float*)d_in[0];
  const float* st = (const float*)d_in[1];
  const float* W1 = (const float*)d_in[2];
  const float* W2 = (const float*)d_in[3];
  const float* a  = (const float*)d_in[4];
  const float* b  = (const float*)d_in[5];
  const float* c  = (const float*)d_in[6];
  const float* d  = (const float*)d_in[7];
  const float* th = (const float*)d_in[8];
  const float* dt = (const float*)d_in[9];
  const float* lk = (const float*)d_in[10];
  const int N = in_sizes[4];          // a has N elements
  const int T = in_sizes[0] / N;

  float* o_s  = (float*)d_out;               // outputs  [T,N]
  float* o_st = o_s + (long)T * N;           // states   [T,2,N]
  float* o_dm = o_st + 2L * (long)T * N;     // decoded  [T,1]

  int*   cnts = (int*)d_ws;                  // N
  int*   cols = cnts + N;                    // N*CAP
  float* wts  = (float*)(cols + (long)N * CAP); // N*CAP
  float* rbuf = wts + (long)N * CAP;         // T

  sparsify_kernel<<<N, 256, 0, stream>>>(W1, N, cnts, cols, wts);
  const int nblk = (N + 63) / 64;
  izh_pipe_kernel<<<nblk, 256, 0, stream>>>(X, st, a, b, c, d, th, dt, W1,
                                            cnts, cols, wts, o_s, o_st, T, N);
  decode_dot_kernel<<<(T + 15) / 16, 256, 0, stream>>>(o_s, W2, rbuf, T, N);
  decode_scan_kernel<<<1, 64, 0, stream>>>(rbuf, lk, o_dm, T);
}

// Round 5
// 611.086 us; speedup vs baseline: 1.1331x; 1.1331x over previous
//
#include <hip/hip_runtime.h>

#define CAP 32
#define K 16              // steps per batch
#define R 2               // batches per group (barrier period = R*K steps)
#define RING 4            // LDS ring slots
#define GROUP (R * K)     // 32 steps between barriers

// ---------------------------------------------------------------------------
// Kernel 1: runtime sparsification of W1 (nnz=1/row here) + zero rbuf.
// ---------------------------------------------------------------------------
__global__ void sparsify_kernel(const float* __restrict__ W1, int N, int T,
                                int* __restrict__ cnts, int* __restrict__ cols,
                                float* __restrict__ wts, float* __restrict__ rbuf) {
  __shared__ int scnt;
  const int row = blockIdx.x;
  if (threadIdx.x == 0) scnt = 0;
  __syncthreads();
  const float* wr = W1 + (long)row * N;
  for (int k = threadIdx.x; k < N; k += blockDim.x) {
    float w = wr[k];
    if (w != 0.0f) {
      int slot = atomicAdd(&scnt, 1);
      if (slot < CAP) {
        cols[row * CAP + slot] = k;
        wts[row * CAP + slot] = w;
      }
    }
  }
  __syncthreads();
  if (threadIdx.x == 0) {
    cnts[row] = scnt;
    if (scnt == 0) { cols[row * CAP] = 0; wts[row * CAP] = 0.0f; }
  }
  // zero the decode partial buffer (ws is re-poisoned before every launch)
  for (int i = blockIdx.x * blockDim.x + threadIdx.x; i < T;
       i += gridDim.x * blockDim.x)
    rbuf[i] = 0.0f;
}

// ---------------------------------------------------------------------------
// Kernel 2: warm input_batch into LLC so the loader wave's per-group vmcnt
// drain is ~LLC latency, comfortably inside its slack.
// ---------------------------------------------------------------------------
__global__ void touch_kernel(const float4* __restrict__ x4, long n4,
                             float* __restrict__ dump) {
  long i = (long)blockIdx.x * blockDim.x + threadIdx.x;
  const long stride = (long)gridDim.x * blockDim.x;
  float acc = 0.f;
  for (; i < n4; i += stride) {
    float4 v = x4[i];
    acc += v.x + v.y + v.z + v.w;
  }
  if (acc == 1234.56789f) dump[blockIdx.x & 1023] = acc;  // defeat DCE
}

// ---------------------------------------------------------------------------
// Kernel 3: pipelined recurrence. Block = 320 thr (5 waves) per 64 neurons.
//   wave0: compute (LDS in/out only inside the loop; 17 VALU/step)
//   wave1: loader — global x -> (I=w0*x) -> xbuf ring, 2-group reg pipeline
//   wave2: s-writer — df -> s, float4 stores, fused W2-dot (exact atomics)
//   wave3/4: v/u writers — strided LDS reads, coalesced dword stores
// One barrier per GROUP=32 steps. Barrier counts identical on all waves.
// ---------------------------------------------------------------------------
__global__ void __launch_bounds__(320, 1) izh_pipe_kernel(
    const float* __restrict__ X, const float* __restrict__ state,
    const float* __restrict__ a, const float* __restrict__ b,
    const float* __restrict__ c, const float* __restrict__ d,
    const float* __restrict__ th, const float* __restrict__ dtv,
    const float* __restrict__ W1, const float* __restrict__ W2,
    const int* __restrict__ cnts, const int* __restrict__ cols,
    const float* __restrict__ wts,
    float* __restrict__ o_s, float* __restrict__ o_st,
    float* __restrict__ rbuf,
    int T, int N)
{
#pragma clang fp contract(off)
  __shared__ float xbuf[RING][K][64];       // staged I = w0*x
  __shared__ float dbuf[RING][K][64];       // df = vn - thresh (spike = df>0)
  __shared__ float vubuf[RING][K][64][2];   // packed (v,u)

  const int wid  = threadIdx.x >> 6;        // 0..4
  const int lane = threadIdx.x & 63;
  const int base = blockIdx.x * 64;
  const int gn   = base + lane;
  const int B    = T / K;
  const int G    = B / R;                   // groups of 32 steps
  const long N2  = 2L * N;

  bool elig = (base + 64 <= N) && ((N & 3) == 0);
  if (elig) elig = (cnts[gn] == 1) && (dtv[gn] == 1.0f);
  const bool fast = (__ballot(elig) == ~0ULL);

  if (fast) {
    if (wid == 0) {
      // ================= compute wave =================
      float v = state[gn], u = state[N + gn];
      const float bn = b[gn], cn = c[gn], dn = d[gn], thn = th[gn];
      const float Pn = dtv[gn] * a[gn];     // same operands/order as ref dt*a
      const float w0g = wts[gn * CAP];
      const int   c0g = cols[gn * CAP];
      const float W2v = W2[gn];
      __syncthreads();
      for (int g = 0; g < G; ++g) {
#pragma unroll
        for (int j = 0; j < R; ++j) {
          const int slot = (g * R + j) & (RING - 1);
#pragma unroll
          for (int i = 0; i < K; ++i) {
            const float I = xbuf[slot][i][lane];     // pre-scaled by loader
            float t1 = 0.04f * v; float t2 = t1 * v; float t3 = 5.0f * v;
            float t4 = t2 + t3;  float t5 = t4 + 140.0f; float t6 = t5 - u;
            float t7 = t6 + I;   float vn = v + t7;       // dt==1: exact
            float q1 = bn * v;   float q2 = q1 - u; float q3 = Pn * q2;
            float un = u + q3;
            float df = vn - thn;
            bool sp = df > 0.0f;
            v = sp ? cn : vn;                 // == vn*(1-s)+c*s bitwise
            u = un + (sp ? dn : 0.0f);        // == un + d*s
            dbuf[slot][i][lane]     = df;
            vubuf[slot][i][lane][0] = v;
            vubuf[slot][i][lane][1] = u;
          }
        }
        __syncthreads();
      }
      // ---- tail (T % GROUP != 0): direct global, fused dot ----
      const float* xp = X + c0g;
      for (int t = G * GROUP; t < T; ++t) {
        const float xv = xp[(size_t)t * N];
        const float I = w0g * xv;
        float t1 = 0.04f * v; float t2 = t1 * v; float t3 = 5.0f * v;
        float t4 = t2 + t3;  float t5 = t4 + 140.0f; float t6 = t5 - u;
        float t7 = t6 + I;   float vn = v + t7;
        float q1 = bn * v;   float q2 = q1 - u; float q3 = Pn * q2;
        float un = u + q3;
        float df = vn - thn;
        bool sp = df > 0.0f;
        v = sp ? cn : vn; u = un + (sp ? dn : 0.0f);
        float s_ = sp ? 1.0f : 0.0f;
        o_s[(size_t)t * N + gn] = s_;
        o_st[(size_t)t * N2 + gn] = v;
        o_st[(size_t)t * N2 + N + gn] = u;
        float p = W2v * s_;
        p += __shfl_xor(p, 1);  p += __shfl_xor(p, 2);
        p += __shfl_xor(p, 4);  p += __shfl_xor(p, 8);
        p += __shfl_xor(p, 16); p += __shfl_xor(p, 32);
        if (lane == 0) atomicAdd(rbuf + t, p);
      }
    } else if (wid == 1) {
      // ================= loader wave =================
      const int   c0 = cols[gn * CAP];
      const float w0 = wts[gn * CAP];
      const float* xp = X + c0;
      float xr[GROUP];
      if (G > 0) {                          // group 0 -> LDS now
#pragma unroll
        for (int i = 0; i < GROUP; ++i) xr[i] = xp[(size_t)i * N];
#pragma unroll
        for (int i = 0; i < GROUP; ++i)
          xbuf[(i >> 4) & (RING - 1)][i & 15][lane] = w0 * xr[i];
      }
      if (G > 1) {                          // group 1 -> regs
#pragma unroll
        for (int i = 0; i < GROUP; ++i) xr[i] = xp[(size_t)(GROUP + i) * N];
      }
      __syncthreads();
      for (int g = 0; g < G; ++g) {
        if (g + 1 < G) {                    // LDS-write group g+1 from regs
          const int b0 = (g + 1) * R;
#pragma unroll
          for (int i = 0; i < GROUP; ++i)
            xbuf[(b0 + (i >> 4)) & (RING - 1)][i & 15][lane] = w0 * xr[i];
        }
        if (g + 2 < G) {                    // issue loads for group g+2
#pragma unroll
          for (int i = 0; i < GROUP; ++i)
            xr[i] = xp[(size_t)((g + 2) * GROUP + i) * N];
        }
        __syncthreads();
      }
    } else if (wid == 2) {
      // ================= s-writer + fused W2 dot =================
      const int r = lane >> 4, j4 = lane & 15;
      const float4 w4 = *(const float4*)(W2 + base + 4 * j4);
      auto s_drain = [&](int g) {
        for (int j = 0; j < R; ++j) {
          const int bb = g * R + j, slot = bb & (RING - 1), t0 = bb * K;
#pragma unroll
          for (int i = 0; i < K; i += 4) {
            const int t = t0 + i + r;
            float4 df4 = *(const float4*)&dbuf[slot][i + r][4 * j4];
            float4 s4;
            s4.x = df4.x > 0.0f ? 1.0f : 0.0f;
            s4.y = df4.y > 0.0f ? 1.0f : 0.0f;
            s4.z = df4.z > 0.0f ? 1.0f : 0.0f;
            s4.w = df4.w > 0.0f ? 1.0f : 0.0f;
            *(float4*)(o_s + (size_t)t * N + base + 4 * j4) = s4;
            float p = w4.x * s4.x + w4.y * s4.y + w4.z * s4.z + w4.w * s4.w;
            p += __shfl_xor(p, 1); p += __shfl_xor(p, 2);
            p += __shfl_xor(p, 4); p += __shfl_xor(p, 8);
            if (j4 == 0) atomicAdd(rbuf + t, p);   // exact: multiples of 20
          }
        }
      };
      __syncthreads();
      for (int g = 0; g < G; ++g) {
        if (g > 0) s_drain(g - 1);
        __syncthreads();
      }
      if (G > 0) s_drain(G - 1);
    } else if (wid == 3) {
      // ================= v writer =================
      auto v_drain = [&](int g) {
        for (int j = 0; j < R; ++j) {
          const int bb = g * R + j, slot = bb & (RING - 1), t0 = bb * K;
#pragma unroll
          for (int i = 0; i < K; ++i)
            o_st[(size_t)(t0 + i) * N2 + gn] = vubuf[slot][i][lane][0];
        }
      };
      __syncthreads();
      for (int g = 0; g < G; ++g) {
        if (g > 0) v_drain(g - 1);
        __syncthreads();
      }
      if (G > 0) v_drain(G - 1);
    } else {
      // ================= u writer =================
      auto u_drain = [&](int g) {
        for (int j = 0; j < R; ++j) {
          const int bb = g * R + j, slot = bb & (RING - 1), t0 = bb * K;
#pragma unroll
          for (int i = 0; i < K; ++i)
            o_st[(size_t)(t0 + i) * N2 + N + gn] = vubuf[slot][i][lane][1];
        }
      };
      __syncthreads();
      for (int g = 0; g < G; ++g) {
        if (g > 0) u_drain(g - 1);
        __syncthreads();
      }
      if (G > 0) u_drain(G - 1);
    }
  } else {
    // ---- general fallback: wave0 only, any cnt / dt, fused dot ----
    if (wid != 0) return;
    const bool act = gn < N;
    float v = 0.f, u = 0.f, bn = 0.f, cn = 0.f, dn = 0.f, thn = 0.f;
    float Pn = 0.f, dtn = 1.0f, W2v = 0.f;
    int cnt = 0;
    if (act) {
      v = state[gn]; u = state[N + gn];
      bn = b[gn]; cn = c[gn]; dn = d[gn]; thn = th[gn]; dtn = dtv[gn];
      Pn = dtn * a[gn];
      cnt = cnts[gn];
      W2v = W2[gn];
    }
    for (int t = 0; t < T; ++t) {
      float I = 0.0f;
      if (act) {
        if (cnt <= CAP) {
          for (int j = 0; j < cnt; ++j)
            I = I + wts[gn * CAP + j] * X[(size_t)t * N + cols[gn * CAP + j]];
        } else {
          const float* wr = W1 + (size_t)gn * N;
          const float* xr = X + (size_t)t * N;
          for (int kk = 0; kk < N; ++kk) I = I + wr[kk] * xr[kk];
        }
      }
      float t1 = 0.04f * v; float t2 = t1 * v; float t3 = 5.0f * v;
      float t4 = t2 + t3; float t5 = t4 + 140.0f; float t6 = t5 - u;
      float t7 = t6 + I; float t8 = dtn * t7; float vn = v + t8;
      float q1 = bn * v; float q2 = q1 - u; float q3 = Pn * q2; float un = u + q3;
      float df = vn - thn; bool sp = df > 0.0f;
      v = sp ? cn : vn; u = un + (sp ? dn : 0.0f);
      float s_ = (sp && act) ? 1.0f : 0.0f;
      if (act) {
        o_s[(size_t)t * N + gn] = s_;
        o_st[(size_t)t * N2 + gn] = v;
        o_st[(size_t)t * N2 + N + gn] = u;
      }
      float p = W2v * s_;
      p += __shfl_xor(p, 1);  p += __shfl_xor(p, 2);
      p += __shfl_xor(p, 4);  p += __shfl_xor(p, 8);
      p += __shfl_xor(p, 16); p += __shfl_xor(p, 32);
      if (lane == 0) atomicAdd(rbuf + t, p);
    }
  }
}

// ---------------------------------------------------------------------------
// Kernel 4: dm[t] = leak*dm[t-1] + r[t], chunked affine scan (1 block, 64 thr)
// Tolerance on decoded output is large; reassociation across chunks is fine.
// ---------------------------------------------------------------------------
__global__ void decode_scan_kernel(const float* __restrict__ r,
                                   const float* __restrict__ leakp,
                                   float* __restrict__ out, int T) {
  __shared__ float Bsh[64], Ssh[64];
  const float leakv = leakp[0];
  const int i = threadIdx.x;                 // 0..63
  const int chunk = (T + 63) / 64;
  const int t0 = i * chunk;
  float B = 0.0f;
  for (int j = 0; j < chunk; ++j) {
    int t = t0 + j;
    if (t < T) B = leakv * B + r[t];
  }
  Bsh[i] = B;
  float A = 1.0f, p = leakv; int e = chunk;
  while (e) { if (e & 1) A *= p; p *= p; e >>= 1; }
  __syncthreads();
  if (i == 0) {
    float dm = 0.0f;
    for (int k = 0; k < 64; ++k) { Ssh[k] = dm; dm = A * dm + Bsh[k]; }
  }
  __syncthreads();
  float dm = Ssh[i];
  for (int j = 0; j < chunk; ++j) {
    int t = t0 + j;
    if (t < T) { dm = leakv * dm + r[t]; out[t] = dm; }
  }
}

// ---------------------------------------------------------------------------
extern "C" void kernel_launch(void* const* d_in, const int* in_sizes, int n_in,
                              void* d_out, int out_size, void* d_ws, size_t ws_size,
                              hipStream_t stream) {
  const float* X  = (const float*)d_in[0];
  const float* st = (const float*)d_in[1];
  const float* W1 = (const float*)d_in[2];
  const float* W2 = (const float*)d_in[3];
  const float* a  = (const float*)d_in[4];
  const float* b  = (const float*)d_in[5];
  const float* c  = (const float*)d_in[6];
  const float* d  = (const float*)d_in[7];
  const float* th = (const float*)d_in[8];
  const float* dt = (const float*)d_in[9];
  const float* lk = (const float*)d_in[10];
  const int N = in_sizes[4];          // a has N elements
  const int T = in_sizes[0] / N;

  float* o_s  = (float*)d_out;               // outputs  [T,N]
  float* o_st = o_s + (long)T * N;           // states   [T,2,N]
  float* o_dm = o_st + 2L * (long)T * N;     // decoded  [T,1]

  int*   cnts = (int*)d_ws;                  // N
  int*   cols = cnts + N;                    // N*CAP
  float* wts  = (float*)(cols + (long)N * CAP); // N*CAP
  float* rbuf = wts + (long)N * CAP;         // T
  float* dump = rbuf + T;                    // toucher sink

  sparsify_kernel<<<N, 256, 0, stream>>>(W1, N, T, cnts, cols, wts, rbuf);
  const long n4 = ((long)T * N) / 4;
  touch_kernel<<<1024, 256, 0, stream>>>((const float4*)X, n4, dump);
  const int nblk = (N + 63) / 64;
  izh_pipe_kernel<<<nblk, 320, 0, stream>>>(X, st, a, b, c, d, th, dt, W1, W2,
                                            cnts, cols, wts, o_s, o_st, rbuf,
                                            T, N);
  decode_scan_kernel<<<1, 64, 0, stream>>>(rbuf, lk, o_dm, T);
}